// Round 7
// baseline (132.425 us; speedup 1.0000x reference)
//
#include <hip/hip_runtime.h>

#define BHH 32      // B*H
#define SEQ 2048
#define DH 64
#define BQ 128      // Q rows per block (32 per wave x 4 sq, 8 waves)
#define BK 64       // K/V rows per tile
#define NKT (SEQ / BK)   // 32
#define NQB (SEQ / BQ)   // 16
#define NT  (BHH * NKT)  // 1024 (bh,kt) prep tiles

typedef __attribute__((ext_vector_type(8))) _Float16 half8_t;
typedef __attribute__((ext_vector_type(4))) _Float16 half4_t;
typedef __attribute__((ext_vector_type(4))) float f32x4;

__device__ __forceinline__ void async_copy16(const void* g, const void* lds) {
    __builtin_amdgcn_global_load_lds(
        (const __attribute__((address_space(1))) unsigned int*)g,
        (__attribute__((address_space(3))) unsigned int*)lds, 16, 0, 0);
}

// ---------------------------------------------------------------------------
// Fused prep (unchanged from round 6): blocks [0,NT) = K, [NT,2NT) = V.
//   Kf frag bid=c*2+k0: lane L holds K[16c+(L&15)][32k0+8(L>>4)+j]   (QK^T A-op)
//   Vf frag f=cn*4+c:   lane L holds V[16c+4(L>>4)+j][16cn+(L&15)]   (PV A-op)
// ---------------------------------------------------------------------------
__global__ __launch_bounds__(256) void prep_kv(const float* __restrict__ K,
                                               const float* __restrict__ V,
                                               _Float16* __restrict__ Kf,
                                               _Float16* __restrict__ Vf) {
    __shared__ _Float16 l[64 * 76];
    const int t = threadIdx.x;
    const int wave = t >> 6, lane = t & 63, ln15 = lane & 15, quad = lane >> 4;
    const int row = t >> 2, col0 = (t & 3) * 16;
    int b = blockIdx.x;

    if (b < NT) {                                    // ---- K path ----
        const float4* src = (const float4*)(K + (size_t)b * 4096 + row * 64 + col0);
        #pragma unroll
        for (int q = 0; q < 2; ++q) {
            float4 f0 = src[q * 2], f1 = src[q * 2 + 1];
            half8_t w = { (_Float16)f0.x, (_Float16)f0.y, (_Float16)f0.z, (_Float16)f0.w,
                          (_Float16)f1.x, (_Float16)f1.y, (_Float16)f1.z, (_Float16)f1.w };
            *(half8_t*)&l[row * 72 + col0 + q * 8] = w;
        }
        __syncthreads();
        #pragma unroll
        for (int p = 0; p < 2; ++p) {
            const int bid = wave * 2 + p, c = bid >> 1, k0 = bid & 1;
            half8_t w = *(const half8_t*)&l[(c * 16 + ln15) * 72 + k0 * 32 + quad * 8];
            *(half8_t*)&Kf[(size_t)b * 4096 + bid * 512 + lane * 8] = w;
        }
    } else {                                         // ---- V path ----
        b -= NT;
        const float4* src = (const float4*)(V + (size_t)b * 4096 + row * 64 + col0);
        #pragma unroll
        for (int q = 0; q < 4; ++q) {
            float4 f = src[q];
            half4_t w = { (_Float16)f.x, (_Float16)f.y, (_Float16)f.z, (_Float16)f.w };
            *(half4_t*)&l[row * 76 + col0 + q * 4] = w;
        }
        __syncthreads();
        #pragma unroll
        for (int p = 0; p < 4; ++p) {
            const int f = wave * 4 + p, cn = f >> 2, c = f & 3;
            half4_t w;
            #pragma unroll
            for (int j = 0; j < 4; ++j)
                w[j] = l[(c * 16 + quad * 4 + j) * 76 + cn * 16 + ln15];
            *(half4_t*)&Vf[(size_t)b * 4096 + f * 256 + lane * 4] = w;
        }
    }
}

// ---------------------------------------------------------------------------
// Flash attention: 512 threads = 8 waves = (4 sq q-quarters) x (2 sk k-halves).
// Each wave: 32 Q-rows x 32 K-rows/tile. S^T = K(A) x Q(B) 16x16x32;
// softmax register-resident; O^T += V^T(A) x P^T(B) 16x16x16.
// sk partial O/l combined through LDS at the end.
// ---------------------------------------------------------------------------
__global__ __launch_bounds__(512) void fattn_kernel(
        const float* __restrict__ Q, const _Float16* __restrict__ Kf,
        const _Float16* __restrict__ Vf, float* __restrict__ O) {
    const int bh = blockIdx.x & 31;
    const int r  = blockIdx.x >> 5;                  // 0..15
    const int qb = (r < 8) ? (15 - r) : (r - 8);     // pair r,r+8 sums 34 tiles
    const int tid  = threadIdx.x;
    const int wave = tid >> 6;
    const int lane = tid & 63;
    const int ln15 = lane & 15;
    const int quad = lane >> 4;
    const int sq = wave & 3;                         // q quarter (32 rows)
    const int sk = wave >> 2;                        // k half (32 rows)

    // staging (2 x 16 KB dbuf = 32 KB) overlaid with epilogue combine (35 KB)
    __shared__ __align__(16) float smemF[8832 + 128];
    _Float16* ldsH = (_Float16*)smemF;

    const size_t base = (size_t)bh * SEQ * DH;
    const int q0 = qb * BQ;
    const int qw = q0 + sq * 32;                     // wave's first q row

    // Q fragments (B-operand: n=ln15, k=quad*8+j), scale log2(e)/64 folded
    const float qscale = 1.44269504f / 64.0f;
    half8_t qfrag[2][2];                             // [g][k0]
    #pragma unroll
    for (int g = 0; g < 2; ++g) {
        const float* qp = Q + base + (size_t)(qw + g * 16 + ln15) * DH + quad * 8;
        #pragma unroll
        for (int k0 = 0; k0 < 2; ++k0) {
            float4 a = *(const float4*)(qp + k0 * 32);
            float4 b = *(const float4*)(qp + k0 * 32 + 4);
            qfrag[g][k0] = (half8_t){
                (_Float16)(a.x * qscale), (_Float16)(a.y * qscale),
                (_Float16)(a.z * qscale), (_Float16)(a.w * qscale),
                (_Float16)(b.x * qscale), (_Float16)(b.y * qscale),
                (_Float16)(b.z * qscale), (_Float16)(b.w * qscale) };
        }
    }

    f32x4 acc[2][4] = {};                            // [g][cn] partial O^T
    float l_i[2] = {0.f, 0.f};
    const size_t tb = (size_t)(bh * NKT) * 4096;

    // stage tile kt: 16 KB = 16 x 1KB copies, 2 per wave. K: 0-7, V: 8-15.
    #define STAGE(kt_, b_) do {                                              \
        const size_t toff = tb + (size_t)(kt_) * 4096;                       \
        _Pragma("unroll")                                                    \
        for (int i_ = 0; i_ < 2; ++i_) {                                     \
            const int bid_ = wave * 2 + i_;                                  \
            if (bid_ < 8)                                                    \
                async_copy16(Kf + toff + bid_ * 512 + lane * 8,              \
                             &ldsH[(b_) * 8192 + bid_ * 512]);               \
            else                                                             \
                async_copy16(Vf + toff + (bid_ - 8) * 512 + lane * 8,        \
                             &ldsH[(b_) * 8192 + 4096 + (bid_ - 8) * 512]);  \
        }                                                                    \
    } while (0)

    const int nkt = 2 * qb + 2;
    STAGE(0, 0);
    __syncthreads();

    for (int kt = 0; kt < nkt; ++kt) {
        const _Float16* kvk = &ldsH[(kt & 1) * 8192];
        const _Float16* kvv = kvk + 4096;
        if (kt + 1 < nkt) STAGE(kt + 1, (kt + 1) & 1);

        const int kw = kt * 64 + sk * 32;            // wave's first k row
        if (kw <= qw + 31) {                         // not fully above diagonal
            // ---- S^T = K x Q^T : st[c][g], q=ln15, krow=kw+c*16+quad*4+rr ----
            f32x4 st[2][2];
            #pragma unroll
            for (int c = 0; c < 2; ++c) {
                const int cg = sk * 2 + c;
                half8_t kf0 = *(const half8_t*)&kvk[(cg * 2 + 0) * 512 + lane * 8];
                half8_t kf1 = *(const half8_t*)&kvk[(cg * 2 + 1) * 512 + lane * 8];
                #pragma unroll
                for (int g = 0; g < 2; ++g) {
                    f32x4 a = {};
                    a = __builtin_amdgcn_mfma_f32_16x16x32_f16(kf0, qfrag[g][0], a, 0, 0, 0);
                    a = __builtin_amdgcn_mfma_f32_16x16x32_f16(kf1, qfrag[g][1], a, 0, 0, 0);
                    st[c][g] = a;
                }
            }

            // ---- softmax (register-resident, no running max) ----
            const bool needmask = (kw + 31) > qw;    // tile overlaps diagonal
            half4_t pfrag[2][2];                     // [c][g]
            #pragma unroll
            for (int g = 0; g < 2; ++g) {
                const int rowi = qw + g * 16 + ln15;
                float psum = 0.f;
                #pragma unroll
                for (int c = 0; c < 2; ++c) {
                    #pragma unroll
                    for (int rr = 0; rr < 4; ++rr) {
                        float v = __builtin_amdgcn_exp2f(st[c][g][rr]);
                        if (needmask && (kw + c * 16 + quad * 4 + rr) > rowi) v = 0.f;
                        pfrag[c][g][rr] = (_Float16)v;
                        psum += v;
                    }
                }
                psum += __shfl_xor(psum, 16);
                psum += __shfl_xor(psum, 32);
                l_i[g] += psum;
            }

            // ---- O^T += V^T x P^T ----
            #pragma unroll
            for (int cn = 0; cn < 4; ++cn) {
                #pragma unroll
                for (int c = 0; c < 2; ++c) {
                    const int f = cn * 4 + sk * 2 + c;
                    half4_t vf = *(const half4_t*)&kvv[f * 256 + lane * 4];
                    acc[0][cn] = __builtin_amdgcn_mfma_f32_16x16x16f16(vf, pfrag[c][0], acc[0][cn], 0, 0, 0);
                    acc[1][cn] = __builtin_amdgcn_mfma_f32_16x16x16f16(vf, pfrag[c][1], acc[1][cn], 0, 0, 0);
                }
            }
        }
        __syncthreads();
    }

    // ---- combine sk partials through LDS (stride 68 floats: 16B-aligned rows) ----
    if (sk == 1) {
        #pragma unroll
        for (int g = 0; g < 2; ++g) {
            const int row = sq * 32 + g * 16 + ln15;
            #pragma unroll
            for (int cn = 0; cn < 4; ++cn) {
                float* p = &smemF[row * 68 + cn * 16 + quad * 4];
                p[0] = acc[g][cn][0]; p[1] = acc[g][cn][1];
                p[2] = acc[g][cn][2]; p[3] = acc[g][cn][3];
            }
            smemF[8832 + row] = l_i[g];              // all quads write same value
        }
    }
    __syncthreads();
    if (sk == 0) {
        #pragma unroll
        for (int g = 0; g < 2; ++g) {
            const int row = sq * 32 + g * 16 + ln15;
            const float rl = 1.0f / (l_i[g] + smemF[8832 + row]);
            float* op = O + base + (size_t)(qw + g * 16 + ln15) * DH;
            #pragma unroll
            for (int cn = 0; cn < 4; ++cn) {
                const float* p = &smemF[row * 68 + cn * 16 + quad * 4];
                float4 o;
                o.x = (acc[g][cn][0] + p[0]) * rl;
                o.y = (acc[g][cn][1] + p[1]) * rl;
                o.z = (acc[g][cn][2] + p[2]) * rl;
                o.w = (acc[g][cn][3] + p[3]) * rl;
                *(float4*)(op + cn * 16 + quad * 4) = o;
            }
        }
    }
    #undef STAGE
}

extern "C" void kernel_launch(void* const* d_in, const int* in_sizes, int n_in,
                              void* d_out, int out_size, void* d_ws, size_t ws_size,
                              hipStream_t stream) {
    const float* Q = (const float*)d_in[0];
    const float* K = (const float*)d_in[1];
    const float* V = (const float*)d_in[2];
    float* O = (float*)d_out;
    _Float16* Kf = (_Float16*)d_ws;
    _Float16* Vf = Kf + (size_t)NT * 4096;           // 8 MB each
    prep_kv<<<2 * NT, 256, 0, stream>>>(K, V, Kf, Vf);
    fattn_kernel<<<NQB * BHH, 512, 0, stream>>>(Q, Kf, Vf, O);
}